// Round 6
// baseline (355.630 us; speedup 1.0000x reference)
//
#include <hip/hip_runtime.h>
#include <hip/hip_bf16.h>

#define N 8192
#define Dd 128

typedef short short8 __attribute__((ext_vector_type(8)));
typedef float floatx4 __attribute__((ext_vector_type(4)));

// round-to-nearest-even fp32 -> bf16 (no NaN in inputs)
static __device__ inline unsigned short f2bf(float f) {
    unsigned int u = __float_as_uint(f);
    return (unsigned short)((u + 0x7fffu + ((u >> 16) & 1u)) >> 16);
}
static __device__ inline float bf2f(unsigned short b) {
    return __uint_as_float(((unsigned int)b) << 16);
}

// One wave per row: convert to bf16, store, and compute row norm of the
// *rounded* values so the gram diagonal cancels exactly.
__global__ __launch_bounds__(256) void prep_kernel(const float* __restrict__ z,
                                                   unsigned short* __restrict__ zb,
                                                   float* __restrict__ sq) {
    int row  = blockIdx.x * 4 + (threadIdx.x >> 6);
    int lane = threadIdx.x & 63;
    float2 v = ((const float2*)z)[row * 64 + lane];
    unsigned short b0 = f2bf(v.x);
    unsigned short b1 = f2bf(v.y);
    float f0 = bf2f(b0), f1 = bf2f(b1);
    ushort2 st; st.x = b0; st.y = b1;
    ((ushort2*)zb)[row * 64 + lane] = st;
    float s = f0 * f0 + f1 * f1;
    #pragma unroll
    for (int off = 32; off > 0; off >>= 1) s += __shfl_down(s, off, 64);
    if (lane == 0) sq[row] = s;
}

// Barrier-free wave streamer. K=128 fits in registers: each wave owns a
// 16-row A-fragment (16 VGPRs, loaded once) and streams 16-col B-fragments
// straight from L2 (zb = 2 MB, L2-resident; each wave-load = 16x64B
// segments), 4 MFMAs per tile, exp-epilogue, 4 dword stores. No LDS, no
// __syncthreads -> no vmcnt(0) barrier drains; the store queue backs up
// against HBM and paces the loop at write-drain rate (the R1..R5 tiled
// kernels all plateaued ~2x above the 42us write floor because their
// barrier-phased structure idled the store stream during staging/MFMA).
// Wave tile: 16 rows x 1024 cols (64 tiles of 16); grid = 512 rowgroups
// x 8 col-strips = 4096 waves = 1024 blocks, all co-resident.
__global__ __launch_bounds__(256) void pairsim_kernel(const unsigned short* __restrict__ zb,
                                                      const float* __restrict__ sq,
                                                      float* __restrict__ out) {
    int wid  = blockIdx.x * 4 + (threadIdx.x >> 6);
    int lane = threadIdx.x & 63;
    int m = lane & 15, quad = lane >> 4;

    int rowBase = (wid >> 3) * 16;          // 512 row groups
    int colSeg  = (wid & 7) * 1024;         // 8 strips of 1024 cols

    // A-fragment, resident for the whole kernel.
    // lane m holds A[m][k], k = ks*32 + quad*8 + j  (short8 chunk index
    // within row m: m*16 + ks*4 + quad).
    const short8* Ab = (const short8*)(zb + (size_t)rowBase * Dd);
    short8 af[4];
    #pragma unroll
    for (int ks = 0; ks < 4; ks++) af[ks] = Ab[m * 16 + ks * 4 + quad];

    // Row norms for this wave's 4 output rows (C rows = quad*4 + r).
    float4 srv = *(const float4*)&sq[rowBase + quad * 4];

    // Software prefetch of the first B fragment.
    const short8* Bb = (const short8*)(zb + (size_t)colSeg * Dd);
    short8 bn[4];
    #pragma unroll
    for (int ks = 0; ks < 4; ks++) bn[ks] = Bb[m * 16 + ks * 4 + quad];
    float scn = sq[colSeg + m];

    for (int ct = 0; ct < 64; ct++) {
        short8 bf[4];
        #pragma unroll
        for (int ks = 0; ks < 4; ks++) bf[ks] = bn[ks];
        float sc = scn;

        // prefetch next tile (wrapped at the tail; redundant load, no branch)
        int ctn = (ct + 1) & 63;
        const short8* Bn = (const short8*)(zb + (size_t)(colSeg + ctn * 16) * Dd);
        #pragma unroll
        for (int ks = 0; ks < 4; ks++) bn[ks] = Bn[m * 16 + ks * 4 + quad];
        scn = sq[colSeg + ctn * 16 + m];

        floatx4 acc = {0.f, 0.f, 0.f, 0.f};
        #pragma unroll
        for (int ks = 0; ks < 4; ks++)
            acc = __builtin_amdgcn_mfma_f32_16x16x32_bf16(af[ks], bf[ks], acc, 0, 0, 0);

        int col = colSeg + ct * 16 + m;
        #pragma unroll
        for (int r = 0; r < 4; r++) {
            float e = fminf(2.0f * acc[r] - srv[r] - sc, 0.0f);
            out[(size_t)(rowBase + quad * 4 + r) * N + col] = __expf(e);
        }
    }
}

extern "C" void kernel_launch(void* const* d_in, const int* in_sizes, int n_in,
                              void* d_out, int out_size, void* d_ws, size_t ws_size,
                              hipStream_t stream) {
    const float* z = (const float*)d_in[0];
    unsigned short* zb = (unsigned short*)d_ws;                       // 2 MB bf16 copy
    float* sqv = (float*)((char*)d_ws + (size_t)N * Dd * sizeof(unsigned short)); // 32 KB norms
    float* out = (float*)d_out;

    prep_kernel<<<N / 4, 256, 0, stream>>>(z, zb, sqv);
    pairsim_kernel<<<1024, 256, 0, stream>>>(zb, sqv, out);
}

// Round 7
// 269.497 us; speedup vs baseline: 1.3196x; 1.3196x over previous
//
#include <hip/hip_runtime.h>
#include <hip/hip_bf16.h>

#define N 8192
#define Dd 128

typedef short short8 __attribute__((ext_vector_type(8)));
typedef float floatx4 __attribute__((ext_vector_type(4)));

// round-to-nearest-even fp32 -> bf16 (no NaN in inputs)
static __device__ inline unsigned short f2bf(float f) {
    unsigned int u = __float_as_uint(f);
    return (unsigned short)((u + 0x7fffu + ((u >> 16) & 1u)) >> 16);
}
static __device__ inline float bf2f(unsigned short b) {
    return __uint_as_float(((unsigned int)b) << 16);
}

// One wave per row: convert to bf16, store, and compute row norm of the
// *rounded* values so the gram diagonal cancels exactly.
__global__ __launch_bounds__(256) void prep_kernel(const float* __restrict__ z,
                                                   unsigned short* __restrict__ zb,
                                                   float* __restrict__ sq) {
    int row  = blockIdx.x * 4 + (threadIdx.x >> 6);
    int lane = threadIdx.x & 63;
    float2 v = ((const float2*)z)[row * 64 + lane];
    unsigned short b0 = f2bf(v.x);
    unsigned short b1 = f2bf(v.y);
    float f0 = bf2f(b0), f1 = bf2f(b1);
    ushort2 st; st.x = b0; st.y = b1;
    ((ushort2*)zb)[row * 64 + lane] = st;
    float s = f0 * f0 + f1 * f1;
    #pragma unroll
    for (int off = 32; off > 0; off >>= 1) s += __shfl_down(s, off, 64);
    if (lane == 0) sq[row] = s;
}

// R1 structure EXACTLY (best measured: ~79us kernel portion; 128x128 tile,
// 256 thr, 2x2 waves of 64x64, direct scattered dword stores), with ONE
// change: XCD-band tile swizzle. Dispatch round-robins blockIdx across the
// 8 XCDs, so mapping (blockIdx&7) -> a contiguous 1024-row output band
// makes each XCD's ~64 concurrent blocks cover one full 128-row x 8192-col
// stripe: complete DRAM pages / full 128B lines written in bursts from a
// single (non-shared) L2 instead of 8 L2s interleaving 512B fragments.
// (R6 post-mortem: fragment-direct-from-L2 streaming regressed 2x -- 16x64B
// gathers serialize in L1 and re-read B 4x; LDS staging stays.)
__global__ __launch_bounds__(256, 2) void pairsim_kernel(const unsigned short* __restrict__ zb,
                                                         const float* __restrict__ sq,
                                                         float* __restrict__ out) {
    __shared__ unsigned short lA[128 * 128];
    __shared__ unsigned short lB[128 * 128];

    int l   = blockIdx.x;
    int xcd = l & 7;             // dispatch round-robin -> XCD id (m09)
    int s   = l >> 3;            // 0..511 within XCD
    int by  = xcd * 8 + (s >> 6);// contiguous 8-tile row band per XCD
    int bx  = s & 63;            // row-major col sweep within the band

    int colBase = bx * 128, rowBase = by * 128;
    int t  = threadIdx.x;
    int r0 = t >> 4, cg = t & 15;   // 16 rows x 16 chunks per pass, 8 passes

    const uint4* gA = (const uint4*)(zb + (size_t)rowBase * Dd);
    const uint4* gB = (const uint4*)(zb + (size_t)colBase * Dd);
    uint4 va[8], vb[8];
    #pragma unroll
    for (int i = 0; i < 8; i++) va[i] = gA[(r0 + i * 16) * 16 + cg];
    #pragma unroll
    for (int i = 0; i < 8; i++) vb[i] = gB[(r0 + i * 16) * 16 + cg];

    int scg = ((cg ^ r0) * 8);      // swizzled chunk offset (elements)
    #pragma unroll
    for (int i = 0; i < 8; i++) *(uint4*)&lA[(r0 + i * 16) * 128 + scg] = va[i];
    #pragma unroll
    for (int i = 0; i < 8; i++) *(uint4*)&lB[(r0 + i * 16) * 128 + scg] = vb[i];
    __syncthreads();

    int w = t >> 6, lane = t & 63;
    int wr = (w >> 1) * 64, wc = (w & 1) * 64;   // 2x2 waves -> 64x64 each
    int m = lane & 15, quad = lane >> 4;

    floatx4 zero = {0.f, 0.f, 0.f, 0.f};
    floatx4 acc[4][4];
    #pragma unroll
    for (int i = 0; i < 4; i++)
        #pragma unroll
        for (int j = 0; j < 4; j++) acc[i][j] = zero;

    #pragma unroll
    for (int ks = 0; ks < 4; ks++) {
        short8 af[4], bfr[4];
        int c = ks * 4 + quad;      // 16B chunk index along K
        #pragma unroll
        for (int i = 0; i < 4; i++)
            af[i] = *(const short8*)&lA[(wr + i * 16 + m) * 128 + ((c ^ m) * 8)];
        #pragma unroll
        for (int j = 0; j < 4; j++)
            bfr[j] = *(const short8*)&lB[(wc + j * 16 + m) * 128 + ((c ^ m) * 8)];
        #pragma unroll
        for (int i = 0; i < 4; i++)
            #pragma unroll
            for (int j = 0; j < 4; j++)
                acc[i][j] = __builtin_amdgcn_mfma_f32_16x16x32_bf16(af[i], bfr[j], acc[i][j], 0, 0, 0);
    }

    // Epilogue: exp(-max(sq_r + sq_c - 2g, 0)) straight from C-layout
    // (col = lane&15, row = quad*4 + reg), plain dword stores.
    #pragma unroll
    for (int j = 0; j < 4; j++) {
        int col = colBase + wc + j * 16 + m;
        float sc = sq[col];
        #pragma unroll
        for (int i = 0; i < 4; i++) {
            #pragma unroll
            for (int r = 0; r < 4; r++) {
                int row = rowBase + wr + i * 16 + quad * 4 + r;
                float sr = sq[row];
                float g = acc[i][j][r];
                float e = fminf(2.0f * g - sr - sc, 0.0f);
                out[(size_t)row * N + col] = __expf(e);
            }
        }
    }
}

extern "C" void kernel_launch(void* const* d_in, const int* in_sizes, int n_in,
                              void* d_out, int out_size, void* d_ws, size_t ws_size,
                              hipStream_t stream) {
    const float* z = (const float*)d_in[0];
    unsigned short* zb = (unsigned short*)d_ws;                       // 2 MB bf16 copy
    float* sqv = (float*)((char*)d_ws + (size_t)N * Dd * sizeof(unsigned short)); // 32 KB norms
    float* out = (float*)d_out;

    prep_kernel<<<N / 4, 256, 0, stream>>>(z, zb, sqv);
    pairsim_kernel<<<4096, 256, 0, stream>>>(zb, sqv, out);
}